// Round 3
// baseline (113.709 us; speedup 1.0000x reference)
//
#include <hip/hip_runtime.h>
#include <hip/hip_bf16.h>

typedef __attribute__((ext_vector_type(8))) short short8;
typedef __attribute__((ext_vector_type(4))) float floatx4;
typedef __attribute__((ext_vector_type(4))) unsigned int uintx4;
#define BF16 __hip_bfloat16

__device__ __forceinline__ unsigned short f2bf(float f) {
  unsigned int u = __builtin_bit_cast(unsigned int, f);
  unsigned int r = (u + 0x7FFFu + ((u >> 16) & 1u)) >> 16;
  return (unsigned short)r;
}

__device__ __forceinline__ unsigned int cvt_pk_bf16(float lo, float hi) {
  unsigned int r;
  asm("v_cvt_pk_bf16_f32 %0, %1, %2" : "=v"(r) : "v"(lo), "v"(hi));
  return r;
}

__device__ __forceinline__ void gload_lds16(const void* g, void* l) {
  __builtin_amdgcn_global_load_lds(
      (const __attribute__((address_space(1))) unsigned int*)g,
      (__attribute__((address_space(3))) unsigned int*)l, 16, 0, 0);
}

// ---------- elementwise f32 -> bf16 ----------
__global__ __launch_bounds__(256)
void cvt_bf16(const float* __restrict__ in, unsigned short* __restrict__ out, int n) {
  int i = (blockIdx.x * 256 + threadIdx.x) * 8;
  if (i >= n) return;
  float4 a = *(const float4*)(in + i);
  float4 b = *(const float4*)(in + i + 4);
  short8 v;
  v[0] = (short)f2bf(a.x); v[1] = (short)f2bf(a.y);
  v[2] = (short)f2bf(a.z); v[3] = (short)f2bf(a.w);
  v[4] = (short)f2bf(b.x); v[5] = (short)f2bf(b.y);
  v[6] = (short)f2bf(b.z); v[7] = (short)f2bf(b.w);
  *(short8*)(out + i) = v;
}

// ---------- transpose+convert: in[K][N] f32 -> out[N][K] bf16 ----------
__global__ __launch_bounds__(256)
void transpose_cvt(const float* __restrict__ in, unsigned short* __restrict__ out,
                   int K, int N) {
  __shared__ float tile[64][65];
  const int nb = N >> 6;
  const int tn = blockIdx.x % nb, tk = blockIdx.x / nb;
  const int n0 = tn << 6, k0 = tk << 6;
  const int tid = threadIdx.x;
#pragma unroll
  for (int c = 0; c < 4; ++c) {
    int t = tid + c * 256;            // [0,1024): 64 rows x 16 float4
    int r = t >> 4, col = (t & 15) << 2;
    float4 v = *(const float4*)(in + (size_t)(k0 + r) * N + n0 + col);
    tile[r][col] = v.x; tile[r][col + 1] = v.y;
    tile[r][col + 2] = v.z; tile[r][col + 3] = v.w;
  }
  __syncthreads();
#pragma unroll
  for (int c = 0; c < 2; ++c) {
    int t = tid + c * 256;            // [0,512): 64 n-rows x 8 short8
    int r = t >> 3, col = (t & 7) << 3;   // r = local n, col = local k
    short8 v;
#pragma unroll
    for (int j = 0; j < 8; ++j) v[j] = (short)f2bf(tile[col + j][r]);
    *(short8*)(out + (size_t)(n0 + r) * K + k0 + col) = v;
  }
}

// ---------- GEMM: C[M][N] = A[M][K] @ Bt[N][K]^T + bias ----------
// BK=64: 32 MFMA per barrier-pair; XOR-swizzled both-sides.
// EPI 0: scatter-write qkv bf16 (q,k -> [2][16][2048][64]; v -> [2][16][64][2048])
// EPI 1: plain row-major [M][N] f32 write
template <int EPI>
__global__ __launch_bounds__(256, 2)
void gemm_bt(const BF16* __restrict__ A, const BF16* __restrict__ Bt,
             const float* __restrict__ bias, void* __restrict__ outv,
             int M, int N, int K) {
  const int tid = threadIdx.x;
  const int w = tid >> 6, l = tid & 63;
  const int lr = l & 15, lg = l >> 4;
  const int nbx = N >> 7;
  const int bm = blockIdx.x / nbx, bn = blockIdx.x % nbx;
  const int row0 = bm << 7, col0 = bn << 7;
  const int wr = (w >> 1) << 6, wc = (w & 1) << 6;

  __shared__ __align__(16) BF16 ldsA[128 * 64];
  __shared__ __align__(16) BF16 ldsB[128 * 64];

  floatx4 acc[4][4] = {};
  const int swzl = (lr & 7) << 3;   // read-side XOR (elements); row&7 == lr&7

  for (int k0 = 0; k0 < K; k0 += 64) {
#pragma unroll
    for (int c = 0; c < 4; ++c) {
      int t = w * 64 + l + c * 256;        // [0,1024): 128 rows x 8 chunks(16B)
      int ar = t >> 3;
      int ch = (t & 7) ^ (ar & 7);         // pre-swizzled source chunk
      gload_lds16(A + (size_t)(row0 + ar) * K + k0 + (ch << 3),
                  ldsA + w * 512 + c * 2048);
      gload_lds16(Bt + (size_t)(col0 + ar) * K + k0 + (ch << 3),
                  ldsB + w * 512 + c * 2048);
    }
    __syncthreads();
#pragma unroll
    for (int kk = 0; kk < 64; kk += 32) {
      short8 af[4], bf[4];
#pragma unroll
      for (int m = 0; m < 4; ++m)
        af[m] = *(const short8*)(ldsA + (wr + m * 16 + lr) * 64 + ((kk + lg * 8) ^ swzl));
#pragma unroll
      for (int n = 0; n < 4; ++n)
        bf[n] = *(const short8*)(ldsB + (wc + n * 16 + lr) * 64 + ((kk + lg * 8) ^ swzl));
#pragma unroll
      for (int m = 0; m < 4; ++m)
#pragma unroll
        for (int n = 0; n < 4; ++n)
          acc[m][n] = __builtin_amdgcn_mfma_f32_16x16x32_bf16(af[m], bf[n], acc[m][n], 0, 0, 0);
    }
    __syncthreads();
  }

#pragma unroll
  for (int m = 0; m < 4; ++m)
#pragma unroll
    for (int n = 0; n < 4; ++n)
#pragma unroll
      for (int j = 0; j < 4; ++j) {
        int row = row0 + wr + m * 16 + lg * 4 + j;   // m index (b*2048 + t)
        int col = col0 + wc + n * 16 + lr;           // n index
        float v = acc[m][n][j] + bias[col];
        if (EPI == 0) {
          BF16* out = (BF16*)outv;
          int s = col >> 10, cc = col & 1023;
          int hh = cc >> 6, dd = cc & 63;
          int bb = row >> 11, tt = row & 2047;
          size_t addr;
          if (s == 2)
            addr = (size_t)8388608 + (((size_t)bb * 16 + hh) * 64 + dd) * 2048 + tt;
          else
            addr = (size_t)s * 4194304 + (((size_t)bb * 16 + hh) * 2048 + tt) * 64 + dd;
          out[addr] = __float2bfloat16(v);
        } else {
          float* out = (float*)outv;
          out[(size_t)row * N + col] = v;
        }
      }
}

// ---------- causal flash attention ----------
// q: [2][16][2048][64], k: [2][16][2048][64], vt: [2][16][64][2048]
// y: [2][2048][1024] bf16  (= [B][T][H*D])
// R3 restructure: 512 blocks x 512 threads (8 waves = 2 wave-groups of 4).
// Block (bh, pr) processes q-tiles {31-pr, pr} (same head -> same KV stream).
// Within each q-tile, group 0 takes even KV tiles, group 1 takes odd; static
// max makes partials ADDITIVE, so groups merge with a plain sum in LDS.
// Every block runs exactly ceil((32-pr)/2)+ceil((pr+1)/2) = 17 iterations ->
// perfect balance; 64KB LDS -> 2 blocks/CU -> 16 waves/CU for the whole run
// (was: decay to ~8 waves -> Occupancy 25.6%, VALUBusy 51%).
__global__ __launch_bounds__(512, 4)
void flash_attn(const BF16* __restrict__ qkv, BF16* __restrict__ y) {
  const int T = 2048;
  const int i = blockIdx.x;
  const int xcd = i & 7, s = i >> 3;          // blocks round-robin XCDs
  const int bh = xcd * 4 + (s & 3);           // 4 heads per XCD -> 2MB L2 set
  const int pr = s >> 2;                      // pair index [0,16)
  const int b = bh >> 4, hd = bh & 15;
  const int tid = threadIdx.x, w = tid >> 6, l = tid & 63;
  const int gg = w >> 2, wl = w & 3;          // wave-group, wave-in-group
  const int lr = l & 15, lg = l >> 4;

  const BF16* Q  = qkv + (size_t)bh * T * 64;
  const BF16* Kp = qkv + 4194304 + (size_t)bh * T * 64;
  const BF16* Vt = qkv + 8388608 + (size_t)bh * 64 * T;

  // per-group: K[2][4096] + V[2][4096] bf16 (32KB); group g at smem+g*32768.
  // merge buffer (f32[64][64], 2-way-swizzled) reuses group-1 K0 (rows 0-31)
  // and V0 (rows 32-63) after group-1's loop has drained (vmcnt(0) on last it).
  __shared__ __align__(16) char smem[65536];
  __shared__ float ldsLsum[64];
  BF16* ldsK = (BF16*)(smem + gg * 32768);
  BF16* ldsV = (BF16*)(smem + gg * 32768 + 16384);

  const float C1 = 0.18033688011112042f;   // log2(e)/8
  const float C2 = 17.312340490667562f;    // 12*log2(e)  (static max M=12)
  const int swzl = (lr & 7) << 3;          // read-side XOR (elements)

  // swizzled staging: LDS linear dest, pre-swizzled global source (chunk^row&7)
#define STAGE(JT, BUF)                                                        \
  {                                                                           \
    const int j0_ = (JT) << 6;                                                \
    _Pragma("unroll")                                                         \
    for (int c = 0; c < 2; ++c) {                                             \
      int t = wl * 64 + l + c * 256;                                          \
      int r = t >> 3;                                                         \
      int ch = (t & 7) ^ (r & 7);                                             \
      gload_lds16(Kp + (size_t)(j0_ + r) * 64 + ch * 8,                       \
                  ldsK + (BUF) * 4096 + wl * 512 + c * 2048);                 \
      gload_lds16(Vt + (size_t)r * T + j0_ + ch * 8,                          \
                  ldsV + (BUF) * 4096 + wl * 512 + c * 2048);                 \
    }                                                                         \
  }

  for (int ph = 0; ph < 2; ++ph) {
    const int qt = ph ? pr : 31 - pr;
    const int n = qt + 1;
    const int q0 = qt << 6;
    const int iters = (n + 1) >> 1;

    // Q fragments for this q-tile's 64 rows (both groups use the same rows)
    short8 qf[2];
#pragma unroll
    for (int c = 0; c < 2; ++c)
      qf[c] = *(const short8*)(Q + (size_t)(q0 + wl * 16 + lr) * 64 + c * 32 + lg * 8);

    floatx4 acc_o[4] = {};
    float lsum = 0.f;

    if (ph == 0) STAGE(gg, 0);   // phase-2 prologue is issued inside ph0 merge

    for (int it = 0; it < iters; ++it) {
      const int jt = 2 * it + gg;          // group's KV tile (stride 2)
      const int cur = (it + ph) & 1;       // ph0 prologue->buf0, ph1->buf1
      const int nx = jt + 2;
      if (nx < n) {
        STAGE(nx, cur ^ 1);
        asm volatile("s_waitcnt vmcnt(4)" ::: "memory");   // tile jt done
      } else {
        asm volatile("s_waitcnt vmcnt(0)" ::: "memory");
      }
      __builtin_amdgcn_s_barrier();

      if (jt < n) {   // group 1 idles (barriers only) on last iter when n odd
        const int j0 = jt << 6;
        // S^T = K @ Q^T (swapped): lane holds S[q=q0+wl*16+lr][key=j0+n4*16+lg*4+j]
        floatx4 accs[4] = {};
        __builtin_amdgcn_s_setprio(1);
#pragma unroll
        for (int c = 0; c < 2; ++c)
#pragma unroll
          for (int n4 = 0; n4 < 4; ++n4) {
            short8 kf = *(const short8*)(ldsK + cur * 4096 + (n4 * 16 + lr) * 64 +
                                         ((c * 32 + lg * 8) ^ swzl));
            accs[n4] = __builtin_amdgcn_mfma_f32_16x16x32_bf16(kf, qf[c], accs[n4], 0, 0, 0);
          }
        __builtin_amdgcn_s_setprio(0);

        // static-max softmax in-register: p = 2^(s*log2e/8 - 12*log2e)
        const bool diag = (jt == qt);
        const int qrow = q0 + wl * 16 + lr;
#pragma unroll
        for (int n4 = 0; n4 < 4; ++n4)
#pragma unroll
          for (int j = 0; j < 4; ++j) {
            float p = exp2f(fmaf(accs[n4][j], C1, -C2));
            if (diag && (j0 + n4 * 16 + lg * 4 + j > qrow)) p = 0.f;
            lsum += p;
            accs[n4][j] = p;
          }

        // O += P @ V ; P-fragments built in-register (cvt_pk + permlane swaps)
        __builtin_amdgcn_s_setprio(1);
#pragma unroll
        for (int c = 0; c < 2; ++c) {
          unsigned int a0 = cvt_pk_bf16(accs[2 * c][0], accs[2 * c][1]);
          unsigned int b0 = cvt_pk_bf16(accs[2 * c + 1][0], accs[2 * c + 1][1]);
          unsigned int a1 = cvt_pk_bf16(accs[2 * c][2], accs[2 * c][3]);
          unsigned int b1 = cvt_pk_bf16(accs[2 * c + 1][2], accs[2 * c + 1][3]);
          asm("v_permlane32_swap_b32 %0, %1" : "+v"(a0), "+v"(b0));
          asm("v_permlane32_swap_b32 %0, %1" : "+v"(a1), "+v"(b1));
          asm("v_permlane16_swap_b32 %0, %1" : "+v"(a0), "+v"(b0));
          asm("v_permlane16_swap_b32 %0, %1" : "+v"(a1), "+v"(b1));
          uintx4 pw;
          pw[0] = a0; pw[1] = a1; pw[2] = b0; pw[3] = b1;
          short8 pf = __builtin_bit_cast(short8, pw);
#pragma unroll
          for (int n4 = 0; n4 < 4; ++n4) {
            short8 vf = *(const short8*)(ldsV + cur * 4096 + (n4 * 16 + lr) * 64 +
                                         ((c * 32 + lg * 8) ^ swzl));
            acc_o[n4] = __builtin_amdgcn_mfma_f32_16x16x32_bf16(pf, vf, acc_o[n4], 0, 0, 0);
          }
        }
        __builtin_amdgcn_s_setprio(0);
      }
      __builtin_amdgcn_s_barrier();
    }

    // ---- merge the two groups' partials (static max -> plain sums) ----
    __syncthreads();                       // all loops drained (vmcnt0 on last it)
    if (ph == 0) STAGE(gg, 1);             // overlap: prologue for phase 2
    lsum += __shfl_xor(lsum, 16, 64);
    lsum += __shfl_xor(lsum, 32, 64);      // per-lane: full row sum for row wl*16+lr
    if (gg == 1) {
      if (lg == 0) ldsLsum[wl * 16 + lr] = lsum;
#pragma unroll
      for (int n4 = 0; n4 < 4; ++n4)
#pragma unroll
        for (int j = 0; j < 4; ++j) {
          int row = wl * 16 + lg * 4 + j;
          int col = (n4 * 16 + lr) ^ (((row >> 2) & 3) << 4);   // 2-way banks
          float* mp = (float*)(smem + 32768 + (row & 32) * 512);
          mp[(row & 31) * 64 + col] = acc_o[n4][j];
        }
    }
    __syncthreads();
    if (gg == 0) {
      float tot = lsum + ldsLsum[wl * 16 + lr];
      float inv_own = 1.0f / tot;
      float inv[4];
#pragma unroll
      for (int j = 0; j < 4; ++j) inv[j] = __shfl(inv_own, lg * 4 + j, 64);
#pragma unroll
      for (int n4 = 0; n4 < 4; ++n4)
#pragma unroll
        for (int j = 0; j < 4; ++j) {
          int row = wl * 16 + lg * 4 + j;
          int col = (n4 * 16 + lr) ^ (((row >> 2) & 3) << 4);
          float* mp = (float*)(smem + 32768 + (row & 32) * 512);
          float v = acc_o[n4][j] + mp[(row & 31) * 64 + col];
          y[((size_t)b * 2048 + q0 + row) * 1024 + hd * 64 + n4 * 16 + lr] =
              __float2bfloat16(v * inv[j]);
        }
    }
    __syncthreads();                       // mrg reads done before next-phase buf0 stage
  }
#undef STAGE
}

extern "C" void kernel_launch(void* const* d_in, const int* in_sizes, int n_in,
                              void* d_out, int out_size, void* d_ws, size_t ws_size,
                              hipStream_t stream) {
  const float* x      = (const float*)d_in[0];
  const float* W_attn = (const float*)d_in[1];
  const float* b_attn = (const float*)d_in[2];
  const float* W_proj = (const float*)d_in[3];
  const float* b_proj = (const float*)d_in[4];
  float* out = (float*)d_out;
  BF16* ws  = (BF16*)d_ws;

  BF16* xb      = ws;                               // [4096][1024]
  BF16* wt_attn = xb + 4194304;                     // [3072][1024]
  BF16* wt_proj = wt_attn + 3145728;                // [1024][1024]
  BF16* qkv     = wt_proj + 1048576;                // q,k,vt (12582912 elems)
  BF16* y       = qkv + 12582912;                   // [4096][1024]

  hipLaunchKernelGGL(cvt_bf16, dim3(2048), dim3(256), 0, stream,
                     x, (unsigned short*)xb, 4194304);
  hipLaunchKernelGGL(transpose_cvt, dim3(48 * 16), dim3(256), 0, stream,
                     W_attn, (unsigned short*)wt_attn, 1024, 3072);
  hipLaunchKernelGGL(transpose_cvt, dim3(16 * 16), dim3(256), 0, stream,
                     W_proj, (unsigned short*)wt_proj, 1024, 1024);
  hipLaunchKernelGGL(gemm_bt<0>, dim3(32 * 24), dim3(256), 0, stream,
                     xb, wt_attn, b_attn, (void*)qkv, 4096, 3072, 1024);
  hipLaunchKernelGGL(flash_attn, dim3(512), dim3(512), 0, stream, qkv, y);
  hipLaunchKernelGGL(gemm_bt<1>, dim3(32 * 8), dim3(256), 0, stream,
                     y, wt_proj, b_proj, (void*)out, 4096, 1024, 1024);
}

// Round 4
// 113.436 us; speedup vs baseline: 1.0024x; 1.0024x over previous
//
#include <hip/hip_runtime.h>
#include <hip/hip_bf16.h>

typedef __attribute__((ext_vector_type(8))) short short8;
typedef __attribute__((ext_vector_type(4))) float floatx4;
typedef __attribute__((ext_vector_type(4))) unsigned int uintx4;
#define BF16 __hip_bfloat16

__device__ __forceinline__ unsigned short f2bf(float f) {
  unsigned int u = __builtin_bit_cast(unsigned int, f);
  unsigned int r = (u + 0x7FFFu + ((u >> 16) & 1u)) >> 16;
  return (unsigned short)r;
}

__device__ __forceinline__ unsigned int cvt_pk_bf16(float lo, float hi) {
  unsigned int r;
  asm("v_cvt_pk_bf16_f32 %0, %1, %2" : "=v"(r) : "v"(lo), "v"(hi));
  return r;
}

__device__ __forceinline__ void gload_lds16(const void* g, void* l) {
  __builtin_amdgcn_global_load_lds(
      (const __attribute__((address_space(1))) unsigned int*)g,
      (__attribute__((address_space(3))) unsigned int*)l, 16, 0, 0);
}

// ---------- elementwise f32 -> bf16 ----------
__global__ __launch_bounds__(256)
void cvt_bf16(const float* __restrict__ in, unsigned short* __restrict__ out, int n) {
  int i = (blockIdx.x * 256 + threadIdx.x) * 8;
  if (i >= n) return;
  float4 a = *(const float4*)(in + i);
  float4 b = *(const float4*)(in + i + 4);
  short8 v;
  v[0] = (short)f2bf(a.x); v[1] = (short)f2bf(a.y);
  v[2] = (short)f2bf(a.z); v[3] = (short)f2bf(a.w);
  v[4] = (short)f2bf(b.x); v[5] = (short)f2bf(b.y);
  v[6] = (short)f2bf(b.z); v[7] = (short)f2bf(b.w);
  *(short8*)(out + i) = v;
}

// ---------- transpose+convert: in[K][N] f32 -> out[N][K] bf16 ----------
__global__ __launch_bounds__(256)
void transpose_cvt(const float* __restrict__ in, unsigned short* __restrict__ out,
                   int K, int N) {
  __shared__ float tile[64][65];
  const int nb = N >> 6;
  const int tn = blockIdx.x % nb, tk = blockIdx.x / nb;
  const int n0 = tn << 6, k0 = tk << 6;
  const int tid = threadIdx.x;
#pragma unroll
  for (int c = 0; c < 4; ++c) {
    int t = tid + c * 256;            // [0,1024): 64 rows x 16 float4
    int r = t >> 4, col = (t & 15) << 2;
    float4 v = *(const float4*)(in + (size_t)(k0 + r) * N + n0 + col);
    tile[r][col] = v.x; tile[r][col + 1] = v.y;
    tile[r][col + 2] = v.z; tile[r][col + 3] = v.w;
  }
  __syncthreads();
#pragma unroll
  for (int c = 0; c < 2; ++c) {
    int t = tid + c * 256;            // [0,512): 64 n-rows x 8 short8
    int r = t >> 3, col = (t & 7) << 3;   // r = local n, col = local k
    short8 v;
#pragma unroll
    for (int j = 0; j < 8; ++j) v[j] = (short)f2bf(tile[col + j][r]);
    *(short8*)(out + (size_t)(n0 + r) * K + k0 + col) = v;
  }
}

// ---------- GEMM: C[M][N] = A[M][K] @ Bt[N][K]^T + bias ----------
// BK=64: 32 MFMA per barrier-pair; XOR-swizzled both-sides.
// EPI 0: scatter-write qkv bf16 (q,k -> [2][16][2048][64]; v -> [2][16][64][2048])
// EPI 1: plain row-major [M][N] f32 write
template <int EPI>
__global__ __launch_bounds__(256, 2)
void gemm_bt(const BF16* __restrict__ A, const BF16* __restrict__ Bt,
             const float* __restrict__ bias, void* __restrict__ outv,
             int M, int N, int K) {
  const int tid = threadIdx.x;
  const int w = tid >> 6, l = tid & 63;
  const int lr = l & 15, lg = l >> 4;
  const int nbx = N >> 7;
  const int bm = blockIdx.x / nbx, bn = blockIdx.x % nbx;
  const int row0 = bm << 7, col0 = bn << 7;
  const int wr = (w >> 1) << 6, wc = (w & 1) << 6;

  __shared__ __align__(16) BF16 ldsA[128 * 64];
  __shared__ __align__(16) BF16 ldsB[128 * 64];

  floatx4 acc[4][4] = {};
  const int swzl = (lr & 7) << 3;   // read-side XOR (elements); row&7 == lr&7

  for (int k0 = 0; k0 < K; k0 += 64) {
#pragma unroll
    for (int c = 0; c < 4; ++c) {
      int t = w * 64 + l + c * 256;        // [0,1024): 128 rows x 8 chunks(16B)
      int ar = t >> 3;
      int ch = (t & 7) ^ (ar & 7);         // pre-swizzled source chunk
      gload_lds16(A + (size_t)(row0 + ar) * K + k0 + (ch << 3),
                  ldsA + w * 512 + c * 2048);
      gload_lds16(Bt + (size_t)(col0 + ar) * K + k0 + (ch << 3),
                  ldsB + w * 512 + c * 2048);
    }
    __syncthreads();
#pragma unroll
    for (int kk = 0; kk < 64; kk += 32) {
      short8 af[4], bf[4];
#pragma unroll
      for (int m = 0; m < 4; ++m)
        af[m] = *(const short8*)(ldsA + (wr + m * 16 + lr) * 64 + ((kk + lg * 8) ^ swzl));
#pragma unroll
      for (int n = 0; n < 4; ++n)
        bf[n] = *(const short8*)(ldsB + (wc + n * 16 + lr) * 64 + ((kk + lg * 8) ^ swzl));
#pragma unroll
      for (int m = 0; m < 4; ++m)
#pragma unroll
        for (int n = 0; n < 4; ++n)
          acc[m][n] = __builtin_amdgcn_mfma_f32_16x16x32_bf16(af[m], bf[n], acc[m][n], 0, 0, 0);
    }
    __syncthreads();
  }

#pragma unroll
  for (int m = 0; m < 4; ++m)
#pragma unroll
    for (int n = 0; n < 4; ++n)
#pragma unroll
      for (int j = 0; j < 4; ++j) {
        int row = row0 + wr + m * 16 + lg * 4 + j;   // m index (b*2048 + t)
        int col = col0 + wc + n * 16 + lr;           // n index
        float v = acc[m][n][j] + bias[col];
        if (EPI == 0) {
          BF16* out = (BF16*)outv;
          int s = col >> 10, cc = col & 1023;
          int hh = cc >> 6, dd = cc & 63;
          int bb = row >> 11, tt = row & 2047;
          size_t addr;
          if (s == 2)
            addr = (size_t)8388608 + (((size_t)bb * 16 + hh) * 64 + dd) * 2048 + tt;
          else
            addr = (size_t)s * 4194304 + (((size_t)bb * 16 + hh) * 2048 + tt) * 64 + dd;
          out[addr] = __float2bfloat16(v);
        } else {
          float* out = (float*)outv;
          out[(size_t)row * N + col] = v;
        }
      }
}

// ---------- causal flash attention, KV-half-split blocks ----------
// q: [2][16][2048][64], k: [2][16][2048][64], vt: [2][16][64][2048]
// R4: 2048 blocks x 256 thr (4 waves, NO lockstep regression of R3).
// Job = (bh, qt, par): even/odd KV tiles of one 64-row q-tile (sizes 0..16,
// dispatched size-descending -> refill queue keeps ~20 waves/CU). Static-max
// softmax makes partials additive: block writes un-normalized O (f32) + row
// lsums; attn_merge sums the two halves and normalizes.
// VALU diet: diag-mask peeled out of main loop; staging pointers
// strength-reduced (+= const per tile); no normalize in epilogue.
__global__ __launch_bounds__(256, 5)
void flash_attn(const BF16* __restrict__ qkv, float* __restrict__ PO,
                float* __restrict__ PL) {
  const int T = 2048;
  const int bid = blockIdx.x;
  const int J = bid >> 5;          // 0..63, size-descending (qt = 31 - J/2)
  const int bh = bid & 31;         // low 3 bits -> XCD; 4 heads per XCD L2
  const int qt = 31 - (J >> 1);
  const int par = J & 1;
  const int q0 = qt << 6;
  const int n = qt + 1;
  const int iters = (n - par + 1) >> 1;     // tiles jt = par, par+2, ...
  const int tid = threadIdx.x, w = tid >> 6, l = tid & 63;
  const int lr = l & 15, lg = l >> 4;

  const BF16* Q  = qkv + (size_t)bh * (T * 64);
  const BF16* Kp = qkv + 4194304 + (size_t)bh * (T * 64);
  const BF16* Vt = qkv + 8388608 + (size_t)bh * (64 * T);

  __shared__ __align__(16) BF16 ldsK[2][4096];
  __shared__ __align__(16) BF16 ldsV[2][4096];   // 32KB total -> 5 blocks/CU

  const float C1 = 0.18033688011112042f;   // log2(e)/8
  const float C2 = 17.312340490667562f;    // 12*log2(e)  (static max M=12)
  const int swzl = (lr & 7) << 3;          // read-side XOR (elements)

  // Q fragments for this wave's 16 rows (global, no LDS)
  short8 qf[2];
#pragma unroll
  for (int c = 0; c < 2; ++c)
    qf[c] = *(const short8*)(Q + (size_t)(q0 + w * 16 + lr) * 64 + c * 32 + lg * 8);

  floatx4 acc_o[4] = {};
  floatx4 lsum4 = {0.f, 0.f, 0.f, 0.f};

  // strength-reduced staging pointers: lane's slice for tile `par`;
  // advance K by 2 tiles (8192 elems), V by 2 tiles (128 elems) per STAGE2.
  const int t0 = w * 64 + l, t1 = t0 + 256;
  const int r0 = t0 >> 3, ch0 = (t0 & 7) ^ (r0 & 7);
  const int r1 = t1 >> 3, ch1 = (t1 & 7) ^ (r1 & 7);
  const BF16* kg0 = Kp + (((size_t)(par * 64 + r0)) << 6) + ch0 * 8;
  const BF16* kg1 = Kp + (((size_t)(par * 64 + r1)) << 6) + ch1 * 8;
  const BF16* vg0 = Vt + (size_t)r0 * T + par * 64 + ch0 * 8;
  const BF16* vg1 = Vt + (size_t)r1 * T + par * 64 + ch1 * 8;

#define STAGE2(BUF)                                           \
  {                                                           \
    gload_lds16(kg0, &ldsK[BUF][w * 512]);                    \
    gload_lds16(vg0, &ldsV[BUF][w * 512]);                    \
    gload_lds16(kg1, &ldsK[BUF][w * 512 + 2048]);             \
    gload_lds16(vg1, &ldsV[BUF][w * 512 + 2048]);             \
    kg0 += 8192; kg1 += 8192; vg0 += 128; vg1 += 128;         \
  }

#define TILE(IT, MASKED)                                                      \
  {                                                                           \
    const int cur_ = (IT) & 1;                                                \
    if ((IT) + 1 < iters) {                                                   \
      STAGE2(cur_ ^ 1);                                                       \
      asm volatile("s_waitcnt vmcnt(4)" ::: "memory");                        \
    } else {                                                                  \
      asm volatile("s_waitcnt vmcnt(0)" ::: "memory");                        \
    }                                                                         \
    __builtin_amdgcn_s_barrier();                                             \
    floatx4 accs[4] = {};                                                     \
    __builtin_amdgcn_s_setprio(1);                                            \
    _Pragma("unroll")                                                         \
    for (int c = 0; c < 2; ++c)                                               \
      _Pragma("unroll")                                                       \
      for (int n4 = 0; n4 < 4; ++n4) {                                        \
        short8 kf = *(const short8*)(&ldsK[cur_][(n4 * 16 + lr) * 64 +        \
                                                ((c * 32 + lg * 8) ^ swzl)]); \
        accs[n4] = __builtin_amdgcn_mfma_f32_16x16x32_bf16(kf, qf[c], accs[n4], 0, 0, 0); \
      }                                                                       \
    __builtin_amdgcn_s_setprio(0);                                            \
    _Pragma("unroll")                                                         \
    for (int n4 = 0; n4 < 4; ++n4)                                            \
      _Pragma("unroll")                                                       \
      for (int j = 0; j < 4; ++j) {                                           \
        float p = exp2f(fmaf(accs[n4][j], C1, -C2));                          \
        if (MASKED && (n4 * 16 + lg * 4 + j > w * 16 + lr)) p = 0.f;          \
        lsum4[j] += p;                                                        \
        accs[n4][j] = p;                                                      \
      }                                                                       \
    __builtin_amdgcn_s_setprio(1);                                            \
    _Pragma("unroll")                                                         \
    for (int c = 0; c < 2; ++c) {                                             \
      unsigned int a0 = cvt_pk_bf16(accs[2 * c][0], accs[2 * c][1]);          \
      unsigned int b0 = cvt_pk_bf16(accs[2 * c + 1][0], accs[2 * c + 1][1]);  \
      unsigned int a1 = cvt_pk_bf16(accs[2 * c][2], accs[2 * c][3]);          \
      unsigned int b1 = cvt_pk_bf16(accs[2 * c + 1][2], accs[2 * c + 1][3]);  \
      asm("v_permlane32_swap_b32 %0, %1" : "+v"(a0), "+v"(b0));               \
      asm("v_permlane32_swap_b32 %0, %1" : "+v"(a1), "+v"(b1));               \
      asm("v_permlane16_swap_b32 %0, %1" : "+v"(a0), "+v"(b0));               \
      asm("v_permlane16_swap_b32 %0, %1" : "+v"(a1), "+v"(b1));               \
      uintx4 pw; pw[0] = a0; pw[1] = a1; pw[2] = b0; pw[3] = b1;              \
      short8 pf = __builtin_bit_cast(short8, pw);                             \
      _Pragma("unroll")                                                       \
      for (int n4 = 0; n4 < 4; ++n4) {                                        \
        short8 vf = *(const short8*)(&ldsV[cur_][(n4 * 16 + lr) * 64 +        \
                                                ((c * 32 + lg * 8) ^ swzl)]); \
        acc_o[n4] = __builtin_amdgcn_mfma_f32_16x16x32_bf16(pf, vf, acc_o[n4], 0, 0, 0); \
      }                                                                       \
    }                                                                         \
    __builtin_amdgcn_s_setprio(0);                                            \
    __builtin_amdgcn_s_barrier();                                             \
  }

  // peel the diagonal tile (it is the LAST tile of the par==(qt&1) half)
  const int full = iters - ((par == (qt & 1)) ? 1 : 0);
  if (iters > 0) {
    STAGE2(0);
    for (int it = 0; it < full; ++it) TILE(it, false);
    if (full < iters) TILE(full, true);
  }
#undef TILE
#undef STAGE2

  // epilogue: write un-normalized partial O (f32) + per-row lsum
  const int slot = (bh * 32 + qt) * 2 + par;
  float lsum = (lsum4[0] + lsum4[1]) + (lsum4[2] + lsum4[3]);
  lsum += __shfl_xor(lsum, 16, 64);
  lsum += __shfl_xor(lsum, 32, 64);
  if (lg == 0) PL[slot * 64 + w * 16 + lr] = lsum;
  float* po = PO + (size_t)slot * 4096;
#pragma unroll
  for (int n4 = 0; n4 < 4; ++n4)
#pragma unroll
    for (int j = 0; j < 4; ++j)
      po[(w * 16 + lg * 4 + j) * 64 + n4 * 16 + lr] = acc_o[n4][j];
}

// ---------- merge the two KV-halves: y = (OA+OB)/(lA+lB), bf16 ----------
__global__ __launch_bounds__(256)
void attn_merge(const float* __restrict__ PO, const float* __restrict__ PL,
                BF16* __restrict__ y) {
  const int g = blockIdx.x * 256 + threadIdx.x;  // 524288 threads, 8 f32 each
  const int qi = g >> 9;                          // bh*32+qt in [0,1024)
  const int rem = (g & 511) << 3;                 // [0,4096) step 8
  const int r = rem >> 6, d0 = rem & 63;
  const float* A = PO + (size_t)qi * 8192 + rem;
  const float* B = A + 4096;
  const float lA = PL[qi * 128 + r];
  const float lB = PL[qi * 128 + 64 + r];
  const float inv = 1.0f / (lA + lB);
  float4 a0 = *(const float4*)A, a1 = *(const float4*)(A + 4);
  float4 b0 = *(const float4*)B, b1 = *(const float4*)(B + 4);
  const int bh = qi >> 5, qt = qi & 31;
  const int b = bh >> 4, h = bh & 15;
  const int t = qt * 64 + r;
  short8 v;
  v[0] = (short)f2bf((a0.x + b0.x) * inv);
  v[1] = (short)f2bf((a0.y + b0.y) * inv);
  v[2] = (short)f2bf((a0.z + b0.z) * inv);
  v[3] = (short)f2bf((a0.w + b0.w) * inv);
  v[4] = (short)f2bf((a1.x + b1.x) * inv);
  v[5] = (short)f2bf((a1.y + b1.y) * inv);
  v[6] = (short)f2bf((a1.z + b1.z) * inv);
  v[7] = (short)f2bf((a1.w + b1.w) * inv);
  *(short8*)(y + ((size_t)b * 2048 + t) * 1024 + h * 64 + d0) = v;
}

extern "C" void kernel_launch(void* const* d_in, const int* in_sizes, int n_in,
                              void* d_out, int out_size, void* d_ws, size_t ws_size,
                              hipStream_t stream) {
  const float* x      = (const float*)d_in[0];
  const float* W_attn = (const float*)d_in[1];
  const float* b_attn = (const float*)d_in[2];
  const float* W_proj = (const float*)d_in[3];
  const float* b_proj = (const float*)d_in[4];
  float* out = (float*)d_out;
  BF16* ws  = (BF16*)d_ws;

  BF16* xb      = ws;                               // [4096][1024]
  BF16* wt_attn = xb + 4194304;                     // [3072][1024]
  BF16* wt_proj = wt_attn + 3145728;                // [1024][1024]
  BF16* qkv     = wt_proj + 1048576;                // q,k,vt (12582912 elems)
  BF16* y       = qkv + 12582912;                   // [4096][1024]
  float* PO     = (float*)(y + 4194304);            // [2048][64][64] f32 partial O
  float* PL     = PO + 8388608;                     // [2048][64] f32 partial lsum

  hipLaunchKernelGGL(cvt_bf16, dim3(2048), dim3(256), 0, stream,
                     x, (unsigned short*)xb, 4194304);
  hipLaunchKernelGGL(transpose_cvt, dim3(48 * 16), dim3(256), 0, stream,
                     W_attn, (unsigned short*)wt_attn, 1024, 3072);
  hipLaunchKernelGGL(transpose_cvt, dim3(16 * 16), dim3(256), 0, stream,
                     W_proj, (unsigned short*)wt_proj, 1024, 1024);
  hipLaunchKernelGGL(gemm_bt<0>, dim3(32 * 24), dim3(256), 0, stream,
                     xb, wt_attn, b_attn, (void*)qkv, 4096, 3072, 1024);
  hipLaunchKernelGGL(flash_attn, dim3(2048), dim3(256), 0, stream, qkv, PO, PL);
  hipLaunchKernelGGL(attn_merge, dim3(2048), dim3(256), 0, stream, PO, PL, y);
  hipLaunchKernelGGL(gemm_bt<1>, dim3(32 * 8), dim3(256), 0, stream,
                     y, wt_proj, b_proj, (void*)out, 4096, 1024, 1024);
}